// Round 6
// baseline (4637.805 us; speedup 1.0000x reference)
//
#include <hip/hip_runtime.h>

// RelationAwareAttention: B=1, S=2048, D=1024, H=8.
// Inputs fp32 (proved rounds 1-3: bf16-interp NaN'd, fp32-interp didn't).
// OUTPUT fp32 (round-5 insight: bf16-packed output read as fp32 decorrelates
// -> the exact 7.3-7.7 = sqrt(2)*max|ref| signature seen in rounds 3-5).
// Raw torch .view(B,S,H,-1) reshape semantics (faithful to the jax ref):
//   key(h,t) = x[8*(t&255)+h] @ attn_w[t>>8]
// Pipeline, all fp32:
//   tmp = relu(relations @ re_w1 + re_b1); rel = tmp @ re_w2 + re_b2
//   per head h: Kp[t] = key(h,t); L = rel @ Kp^T; P = softmax(L); ctx = P @ x
//               d_out += ctx @ out_w[h*1024:(h+1)*1024, :]
// ws (floats): rel 2M | Kp 2M | ctx 2M | L 4M (tmp aliases L) = 40 MiB.
// d_out doubles as the fp32 accumulator (init with out_b broadcast).

typedef unsigned short u16;

// ---------------- sentinel diagnostic (only if shapes unexpected) ----------------
__launch_bounds__(256)
__global__ void diag_k(float* __restrict__ out, int n, float code) {
    int i = blockIdx.x * 256 + threadIdx.x;
    if (i < n) out[i] = (i == 0) ? code : 0.f;
}

// ---------------- relation encoder layer 1 (K=4) ----------------
__launch_bounds__(256)
__global__ void rel_l1(const float* __restrict__ relations, const float* __restrict__ w1,
                       const float* __restrict__ b1, float* __restrict__ tmp) {
    const int s = blockIdx.x;
    const int d = threadIdx.x * 4;
    float4 rr = *(const float4*)(relations + s * 4);
    float4 w0 = *(const float4*)(w1 + 0 * 1024 + d);
    float4 w1r = *(const float4*)(w1 + 1 * 1024 + d);
    float4 w2r = *(const float4*)(w1 + 2 * 1024 + d);
    float4 w3r = *(const float4*)(w1 + 3 * 1024 + d);
    float4 bb = *(const float4*)(b1 + d);
    float o0 = fmaxf(rr.x * w0.x + rr.y * w1r.x + rr.z * w2r.x + rr.w * w3r.x + bb.x, 0.f);
    float o1 = fmaxf(rr.x * w0.y + rr.y * w1r.y + rr.z * w2r.y + rr.w * w3r.y + bb.y, 0.f);
    float o2 = fmaxf(rr.x * w0.z + rr.y * w1r.z + rr.z * w2r.z + rr.w * w3r.z + bb.z, 0.f);
    float o3 = fmaxf(rr.x * w0.w + rr.y * w1r.w + rr.z * w2r.w + rr.w * w3r.w + bb.w, 0.f);
    *(float4*)&tmp[(size_t)s * 1024 + d] = make_float4(o0, o1, o2, o3);
}

__launch_bounds__(256)
__global__ void init_out(const float* __restrict__ bias, float* __restrict__ oa) {
    const int s = blockIdx.x;
    const int d = threadIdx.x * 4;
    *(float4*)&oa[(size_t)s * 1024 + d] = *(const float4*)(bias + d);
}

// ---------------- fp32 tiled GEMM ----------------
// MODE 0: NN  C[m,n]=sum_k A[m,k]B[k,n]
// MODE 1: NT  C[m,n]=sum_k A[m,k]B[n,k]
// MODE 2: NN + A-row remap (x perm: row=8*(t&255)+head) + B block select (attn_w[t>>8])
// boff = extra element offset into B. ACC: C += result.
constexpr int BM = 128, BN = 64, BK = 16;
constexpr int TM = 8, TN = 4;

template<int MODE, bool ACC>
__launch_bounds__(256)
__global__ void gemm_k(const float* __restrict__ A, const float* __restrict__ B,
                       float* __restrict__ C, const float* __restrict__ bias,
                       int M, int N, int K, int lda, int ldb, int ldc,
                       int head, size_t boff) {
    __shared__ float As[BK][BM + 4];
    __shared__ float Bs[BK][BN + 4];
    const int tid = threadIdx.x;
    const int tx = tid & 15;
    const int ty = tid >> 4;
    const int m0 = blockIdx.y * BM;
    const int n0 = blockIdx.x * BN;

    size_t bofft = boff;
    if (MODE == 2) bofft += (size_t)(m0 >> 8) * 1024 * 1024;  // attn_w[t0>>8]

    float acc[TM][TN];
#pragma unroll
    for (int i = 0; i < TM; ++i)
#pragma unroll
        for (int j = 0; j < TN; ++j) acc[i][j] = 0.f;

    for (int k0 = 0; k0 < K; k0 += BK) {
        // stage A (BM x BK) transposed into As[k][m]
#pragma unroll
        for (int i = 0; i < 2; ++i) {
            int g = tid + i * 256;
            int ar = g >> 2;
            int ac = (g & 3) << 2;
            int grow = m0 + ar;
            if (MODE == 2) grow = ((grow & 255) << 3) + head;  // x row permutation
            size_t idx = (size_t)grow * lda + k0 + ac;
            float4 v = *(const float4*)(A + idx);
            As[ac + 0][ar] = v.x; As[ac + 1][ar] = v.y;
            As[ac + 2][ar] = v.z; As[ac + 3][ar] = v.w;
        }
        // stage B into Bs[k][n]
        if (MODE == 1) {  // B is [N,K] row-major
            int br = tid >> 2;
            int bc = (tid & 3) << 2;
            size_t idx = bofft + (size_t)(n0 + br) * ldb + k0 + bc;
            float4 v = *(const float4*)(B + idx);
            Bs[bc + 0][br] = v.x; Bs[bc + 1][br] = v.y;
            Bs[bc + 2][br] = v.z; Bs[bc + 3][br] = v.w;
        } else {          // B is [K,N] row-major
            int br = tid >> 4;
            int bc = (tid & 15) << 2;
            size_t idx = bofft + (size_t)(k0 + br) * ldb + n0 + bc;
            *(float4*)&Bs[br][bc] = *(const float4*)(B + idx);
        }
        __syncthreads();
#pragma unroll
        for (int k = 0; k < BK; ++k) {
            float a[TM], b[TN];
            *(float4*)&a[0] = *(const float4*)&As[k][ty * TM];
            *(float4*)&a[4] = *(const float4*)&As[k][ty * TM + 4];
            *(float4*)&b[0] = *(const float4*)&Bs[k][tx * TN];
#pragma unroll
            for (int i = 0; i < TM; ++i)
#pragma unroll
                for (int j = 0; j < TN; ++j)
                    acc[i][j] = fmaf(a[i], b[j], acc[i][j]);
        }
        __syncthreads();
    }

    float bv[TN] = {0.f, 0.f, 0.f, 0.f};
    if (bias) {
#pragma unroll
        for (int j = 0; j < TN; ++j) bv[j] = bias[n0 + tx * TN + j];
    }
#pragma unroll
    for (int i = 0; i < TM; ++i) {
        int cm = m0 + ty * TM + i;
        size_t cidx = (size_t)cm * ldc + n0 + tx * TN;
        float4 o = make_float4(acc[i][0] + bv[0], acc[i][1] + bv[1],
                               acc[i][2] + bv[2], acc[i][3] + bv[3]);
        if (ACC) {
            float4 old = *(const float4*)&C[cidx];
            o.x += old.x; o.y += old.y; o.z += old.z; o.w += old.w;
        }
        *(float4*)&C[cidx] = o;
    }
}

// ---------------- row softmax, in place, 2048 cols ----------------
__launch_bounds__(256)
__global__ void softmax_rows(float* __restrict__ P) {
    const int row = blockIdx.x;
    float* p = P + (size_t)row * 2048;
    float4 v0 = ((const float4*)p)[threadIdx.x];
    float4 v1 = ((const float4*)p)[threadIdx.x + 256];
    float m = fmaxf(fmaxf(fmaxf(v0.x, v0.y), fmaxf(v0.z, v0.w)),
                    fmaxf(fmaxf(v1.x, v1.y), fmaxf(v1.z, v1.w)));
#pragma unroll
    for (int off = 32; off; off >>= 1) m = fmaxf(m, __shfl_xor(m, off));
    __shared__ float rm[4], rs[4];
    const int wave = threadIdx.x >> 6;
    if ((threadIdx.x & 63) == 0) rm[wave] = m;
    __syncthreads();
    m = fmaxf(fmaxf(rm[0], rm[1]), fmaxf(rm[2], rm[3]));
    v0.x = __expf(v0.x - m); v0.y = __expf(v0.y - m);
    v0.z = __expf(v0.z - m); v0.w = __expf(v0.w - m);
    v1.x = __expf(v1.x - m); v1.y = __expf(v1.y - m);
    v1.z = __expf(v1.z - m); v1.w = __expf(v1.w - m);
    float s = v0.x + v0.y + v0.z + v0.w + v1.x + v1.y + v1.z + v1.w;
#pragma unroll
    for (int off = 32; off; off >>= 1) s += __shfl_xor(s, off);
    if ((threadIdx.x & 63) == 0) rs[wave] = s;
    __syncthreads();
    s = rs[0] + rs[1] + rs[2] + rs[3];
    const float inv = 1.0f / s;
    v0.x *= inv; v0.y *= inv; v0.z *= inv; v0.w *= inv;
    v1.x *= inv; v1.y *= inv; v1.z *= inv; v1.w *= inv;
    ((float4*)p)[threadIdx.x] = v0;
    ((float4*)p)[threadIdx.x + 256] = v1;
}

extern "C" void kernel_launch(void* const* d_in, const int* in_sizes, int n_in,
                              void* d_out, int out_size, void* d_ws, size_t ws_size,
                              hipStream_t stream) {
    const float* x      = (const float*)d_in[0];
    const float* rels   = (const float*)d_in[1];
    const float* re_w1  = (const float*)d_in[2];
    const float* re_b1  = (const float*)d_in[3];
    const float* re_w2  = (const float*)d_in[4];
    const float* re_b2  = (const float*)d_in[5];
    const float* attn_w = (const float*)d_in[6];
    const float* out_w  = (const float*)d_in[7];
    const float* out_b  = (const float*)d_in[8];
    float* out = (float*)d_out;

    // host-side shape verification (in_sizes is host memory)
    bool dims_ok = (n_in == 9) &&
        in_sizes[0] == 2097152 && in_sizes[1] == 8192 && in_sizes[2] == 4096 &&
        in_sizes[3] == 1024 && in_sizes[4] == 1048576 && in_sizes[5] == 1024 &&
        in_sizes[6] == 8388608 && in_sizes[7] == 8388608 && in_sizes[8] == 1024 &&
        out_size == 2097152;
    bool ws_ok = ws_size >= (size_t)40 * 1024 * 1024;
    if (!dims_ok || !ws_ok) {
        // sentinel: 16384 + 2048*dims_bad + 1024*ws_small + derived-D/16
        int D = (in_sizes[1] > 0) ? (int)(4LL * in_sizes[0] / in_sizes[1]) : 0;
        float code = 16384.f + (dims_ok ? 0.f : 2048.f) + (ws_ok ? 0.f : 1024.f)
                   + (float)((D > 0 && D < 16384) ? D / 16 : 1000);
        int n = out_size;
        diag_k<<<dim3((n + 255) / 256), 256, 0, stream>>>(out, n, code);
        return;
    }

    float* ws  = (float*)d_ws;
    float* rel = ws;               // 2097152
    float* Kp  = rel + 2097152;    // 2097152 (per-head)
    float* ctx = Kp + 2097152;     // 2097152 (per-head)
    float* L   = ctx + 2097152;    // 4194304
    float* tmp = L;                // alias: tmp dead before L written

    // 1. tmp = relu(relations @ re_w1 + re_b1)
    rel_l1<<<dim3(2048), dim3(256), 0, stream>>>(rels, re_w1, re_b1, tmp);
    // 2. rel = tmp @ re_w2 + re_b2
    gemm_k<0, false><<<dim3(16, 16), 256, 0, stream>>>(
        tmp, re_w2, rel, re_b2, 2048, 1024, 1024, 1024, 1024, 1024, 0, 0);
    // 3. out = broadcast(out_b)   (fp32 accumulator IS d_out)
    init_out<<<dim3(2048), dim3(256), 0, stream>>>(out_b, out);
    // 4. per head (raw-reshape semantics)
    for (int h = 0; h < 8; ++h) {
        // Kp[t] = x[8*(t&255)+h] @ attn_w[t>>8]
        gemm_k<2, false><<<dim3(16, 16), 256, 0, stream>>>(
            x, attn_w, Kp, nullptr, 2048, 1024, 1024, 1024, 1024, 1024, h, 0);
        // L = rel @ Kp^T
        gemm_k<1, false><<<dim3(32, 16), 256, 0, stream>>>(
            rel, Kp, L, nullptr, 2048, 2048, 1024, 1024, 1024, 2048, 0, 0);
        softmax_rows<<<dim3(2048), 256, 0, stream>>>(L);
        // ctx = P @ x
        gemm_k<0, false><<<dim3(16, 16), 256, 0, stream>>>(
            L, x, ctx, nullptr, 2048, 1024, 2048, 2048, 1024, 1024, 0, 0);
        // out += ctx @ out_w[h*1024:(h+1)*1024, :]
        gemm_k<0, true><<<dim3(16, 16), 256, 0, stream>>>(
            ctx, out_w, out, nullptr, 2048, 1024, 1024, 1024, 1024, 1024,
            0, (size_t)h * 1024 * 1024);
    }
}

// Round 7
// 3197.918 us; speedup vs baseline: 1.4503x; 1.4503x over previous
//
#include <hip/hip_runtime.h>

// RelationAwareAttention: B=1, S=2048, D=1024, H=8. fp32 in / fp32 out.
// Raw torch .view(B,S,H,-1) reshape semantics: key(h,t) = x[8*(t&255)+h] @ attn_w[t>>8]
// Round-7: occupancy restructure. 64x64 tiles (512-1024 blocks/GEMM vs 256),
// Kp GEMM writes TRANSPOSED output so logits GEMM is NN (kills the 4-way
// bank-conflict NT staging seen in round-6 counters: 2.1M SQ_LDS_BANK_CONFLICT).
// ws (floats): rel 2M | KpT 2M | ctx 2M | L 4M (tmp aliases L) = 40 MiB.
// d_out is the fp32 out-projection accumulator (init = out_b broadcast).

// ---------------- sentinel diagnostic (only if shapes unexpected) ----------------
__launch_bounds__(256)
__global__ void diag_k(float* __restrict__ out, int n, float code) {
    int i = blockIdx.x * 256 + threadIdx.x;
    if (i < n) out[i] = (i == 0) ? code : 0.f;
}

// ---------------- relation encoder layer 1 (K=4) ----------------
__launch_bounds__(256)
__global__ void rel_l1(const float* __restrict__ relations, const float* __restrict__ w1,
                       const float* __restrict__ b1, float* __restrict__ tmp) {
    const int s = blockIdx.x;
    const int d = threadIdx.x * 4;
    float4 rr = *(const float4*)(relations + s * 4);
    float4 w0 = *(const float4*)(w1 + 0 * 1024 + d);
    float4 w1r = *(const float4*)(w1 + 1 * 1024 + d);
    float4 w2r = *(const float4*)(w1 + 2 * 1024 + d);
    float4 w3r = *(const float4*)(w1 + 3 * 1024 + d);
    float4 bb = *(const float4*)(b1 + d);
    float o0 = fmaxf(rr.x * w0.x + rr.y * w1r.x + rr.z * w2r.x + rr.w * w3r.x + bb.x, 0.f);
    float o1 = fmaxf(rr.x * w0.y + rr.y * w1r.y + rr.z * w2r.y + rr.w * w3r.y + bb.y, 0.f);
    float o2 = fmaxf(rr.x * w0.z + rr.y * w1r.z + rr.z * w2r.z + rr.w * w3r.z + bb.z, 0.f);
    float o3 = fmaxf(rr.x * w0.w + rr.y * w1r.w + rr.z * w2r.w + rr.w * w3r.w + bb.w, 0.f);
    *(float4*)&tmp[(size_t)s * 1024 + d] = make_float4(o0, o1, o2, o3);
}

__launch_bounds__(256)
__global__ void init_out(const float* __restrict__ bias, float* __restrict__ oa) {
    const int s = blockIdx.x;
    const int d = threadIdx.x * 4;
    *(float4*)&oa[(size_t)s * 1024 + d] = *(const float4*)(bias + d);
}

// ---------------- fp32 tiled GEMM, 64x64 tile, 256 threads, 4x4/thread ----------
// MODE 0: plain NN. MODE 2: A-row remap (x perm: row=8*(m&255)+head) + B block
//         select (attn_w[m0>>8]; 64-tiles never cross a 256-row boundary).
// TRC: write C transposed (C[n][m], float4 along m) -> used to produce KpT.
// ACC: C += result. boff: extra element offset into B (head select).
constexpr int BM = 64, BN = 64, BK = 16;
constexpr int TM = 4, TN = 4;

template<int MODE, bool ACC, bool TRC>
__launch_bounds__(256)
__global__ void gemm64(const float* __restrict__ A, const float* __restrict__ B,
                       float* __restrict__ C, const float* __restrict__ bias,
                       int M, int N, int K, int lda, int ldb, int ldc,
                       int head, size_t boff) {
    __shared__ float As[BK][BM + 4];
    __shared__ float Bs[BK][BN + 4];
    const int tid = threadIdx.x;
    const int tx = tid & 15;    // n / 4
    const int ty = tid >> 4;    // m / 4
    const int m0 = blockIdx.y * BM;
    const int n0 = blockIdx.x * BN;

    size_t bofft = boff;
    if (MODE == 2) bofft += (size_t)(m0 >> 8) * 1024 * 1024;  // attn_w[t0>>8]

    // A staging indices: 64 rows x 16 cols, one float4 per thread
    const int ar = tid >> 2;             // 0..63
    const int ac = (tid & 3) << 2;       // 0,4,8,12
    int grow = m0 + ar;
    if (MODE == 2) grow = ((grow & 255) << 3) + head;  // x row permutation
    const size_t abase = (size_t)grow * lda + ac;
    // B staging indices: 16 rows x 64 cols, one float4 per thread
    const int br = tid >> 4;             // 0..15
    const int bc = (tid & 15) << 2;      // 0..60
    const size_t bbase = bofft + (size_t)br * ldb + n0 + bc;

    float acc[TM][TN];
#pragma unroll
    for (int i = 0; i < TM; ++i)
#pragma unroll
        for (int j = 0; j < TN; ++j) acc[i][j] = 0.f;

    for (int k0 = 0; k0 < K; k0 += BK) {
        float4 va = *(const float4*)(A + abase + k0);
        float4 vb = *(const float4*)(B + bbase + (size_t)k0 * ldb);
        As[ac + 0][ar] = va.x; As[ac + 1][ar] = va.y;
        As[ac + 2][ar] = va.z; As[ac + 3][ar] = va.w;
        *(float4*)&Bs[br][bc] = vb;
        __syncthreads();
#pragma unroll
        for (int k = 0; k < BK; ++k) {
            float a[TM], b[TN];
            *(float4*)&a[0] = *(const float4*)&As[k][ty * TM];
            *(float4*)&b[0] = *(const float4*)&Bs[k][tx * TN];
#pragma unroll
            for (int i = 0; i < TM; ++i)
#pragma unroll
                for (int j = 0; j < TN; ++j)
                    acc[i][j] = fmaf(a[i], b[j], acc[i][j]);
        }
        __syncthreads();
    }

    if (TRC) {
        // C[n][m] (KpT): float4 along m
#pragma unroll
        for (int j = 0; j < TN; ++j) {
            int cn = n0 + tx * TN + j;
            size_t cidx = (size_t)cn * ldc + m0 + ty * TM;
            *(float4*)&C[cidx] = make_float4(acc[0][j], acc[1][j], acc[2][j], acc[3][j]);
        }
    } else {
        float bv[TN] = {0.f, 0.f, 0.f, 0.f};
        if (bias) {
#pragma unroll
            for (int j = 0; j < TN; ++j) bv[j] = bias[n0 + tx * TN + j];
        }
#pragma unroll
        for (int i = 0; i < TM; ++i) {
            int cm = m0 + ty * TM + i;
            size_t cidx = (size_t)cm * ldc + n0 + tx * TN;
            float4 o = make_float4(acc[i][0] + bv[0], acc[i][1] + bv[1],
                                   acc[i][2] + bv[2], acc[i][3] + bv[3]);
            if (ACC) {
                float4 old = *(const float4*)&C[cidx];
                o.x += old.x; o.y += old.y; o.z += old.z; o.w += old.w;
            }
            *(float4*)&C[cidx] = o;
        }
    }
}

// ---------------- row softmax, in place, 2048 cols ----------------
__launch_bounds__(256)
__global__ void softmax_rows(float* __restrict__ P) {
    const int row = blockIdx.x;
    float* p = P + (size_t)row * 2048;
    float4 v0 = ((const float4*)p)[threadIdx.x];
    float4 v1 = ((const float4*)p)[threadIdx.x + 256];
    float m = fmaxf(fmaxf(fmaxf(v0.x, v0.y), fmaxf(v0.z, v0.w)),
                    fmaxf(fmaxf(v1.x, v1.y), fmaxf(v1.z, v1.w)));
#pragma unroll
    for (int off = 32; off; off >>= 1) m = fmaxf(m, __shfl_xor(m, off));
    __shared__ float rm[4], rs[4];
    const int wave = threadIdx.x >> 6;
    if ((threadIdx.x & 63) == 0) rm[wave] = m;
    __syncthreads();
    m = fmaxf(fmaxf(rm[0], rm[1]), fmaxf(rm[2], rm[3]));
    v0.x = __expf(v0.x - m); v0.y = __expf(v0.y - m);
    v0.z = __expf(v0.z - m); v0.w = __expf(v0.w - m);
    v1.x = __expf(v1.x - m); v1.y = __expf(v1.y - m);
    v1.z = __expf(v1.z - m); v1.w = __expf(v1.w - m);
    float s = v0.x + v0.y + v0.z + v0.w + v1.x + v1.y + v1.z + v1.w;
#pragma unroll
    for (int off = 32; off; off >>= 1) s += __shfl_xor(s, off);
    if ((threadIdx.x & 63) == 0) rs[wave] = s;
    __syncthreads();
    s = rs[0] + rs[1] + rs[2] + rs[3];
    const float inv = 1.0f / s;
    v0.x *= inv; v0.y *= inv; v0.z *= inv; v0.w *= inv;
    v1.x *= inv; v1.y *= inv; v1.z *= inv; v1.w *= inv;
    ((float4*)p)[threadIdx.x] = v0;
    ((float4*)p)[threadIdx.x + 256] = v1;
}

extern "C" void kernel_launch(void* const* d_in, const int* in_sizes, int n_in,
                              void* d_out, int out_size, void* d_ws, size_t ws_size,
                              hipStream_t stream) {
    const float* x      = (const float*)d_in[0];
    const float* rels   = (const float*)d_in[1];
    const float* re_w1  = (const float*)d_in[2];
    const float* re_b1  = (const float*)d_in[3];
    const float* re_w2  = (const float*)d_in[4];
    const float* re_b2  = (const float*)d_in[5];
    const float* attn_w = (const float*)d_in[6];
    const float* out_w  = (const float*)d_in[7];
    const float* out_b  = (const float*)d_in[8];
    float* out = (float*)d_out;

    bool dims_ok = (n_in == 9) &&
        in_sizes[0] == 2097152 && in_sizes[1] == 8192 && in_sizes[2] == 4096 &&
        in_sizes[3] == 1024 && in_sizes[4] == 1048576 && in_sizes[5] == 1024 &&
        in_sizes[6] == 8388608 && in_sizes[7] == 8388608 && in_sizes[8] == 1024 &&
        out_size == 2097152;
    bool ws_ok = ws_size >= (size_t)40 * 1024 * 1024;
    if (!dims_ok || !ws_ok) {
        int D = (in_sizes[1] > 0) ? (int)(4LL * in_sizes[0] / in_sizes[1]) : 0;
        float code = 16384.f + (dims_ok ? 0.f : 2048.f) + (ws_ok ? 0.f : 1024.f)
                   + (float)((D > 0 && D < 16384) ? D / 16 : 1000);
        int n = out_size;
        diag_k<<<dim3((n + 255) / 256), 256, 0, stream>>>(out, n, code);
        return;
    }

    float* ws  = (float*)d_ws;
    float* rel = ws;               // 2097152
    float* KpT = rel + 2097152;    // 2097152 [1024 x 2048] (per-head)
    float* ctx = KpT + 2097152;    // 2097152 (per-head)
    float* L   = ctx + 2097152;    // 4194304
    float* tmp = L;                // alias: tmp dead before L written

    // 1. tmp = relu(relations @ re_w1 + re_b1)
    rel_l1<<<dim3(2048), dim3(256), 0, stream>>>(rels, re_w1, re_b1, tmp);
    // 2. rel = tmp @ re_w2 + re_b2
    gemm64<0, false, false><<<dim3(16, 32), 256, 0, stream>>>(
        tmp, re_w2, rel, re_b2, 2048, 1024, 1024, 1024, 1024, 1024, 0, 0);
    // 3. out = broadcast(out_b)
    init_out<<<dim3(2048), dim3(256), 0, stream>>>(out_b, out);
    // 4. per head (raw-reshape semantics)
    for (int h = 0; h < 8; ++h) {
        // KpT[d][t] = key(h,t)[d] ; transposed write -> logits GEMM is NN
        gemm64<2, false, true><<<dim3(16, 32), 256, 0, stream>>>(
            x, attn_w, KpT, nullptr, 2048, 1024, 1024, 1024, 1024, 2048, h, 0);
        // L = rel @ KpT   (NN)
        gemm64<0, false, false><<<dim3(32, 32), 256, 0, stream>>>(
            rel, KpT, L, nullptr, 2048, 2048, 1024, 1024, 2048, 2048, 0, 0);
        softmax_rows<<<dim3(2048), 256, 0, stream>>>(L);
        // ctx = P @ x   (NN)
        gemm64<0, false, false><<<dim3(16, 32), 256, 0, stream>>>(
            L, x, ctx, nullptr, 2048, 1024, 2048, 2048, 1024, 1024, 0, 0);
        // out += ctx @ out_w[h*1024:(h+1)*1024, :]
        gemm64<0, true, false><<<dim3(16, 32), 256, 0, stream>>>(
            ctx, out_w, out, nullptr, 2048, 1024, 1024, 1024, 1024, 1024,
            0, (size_t)h * 1024 * 1024);
    }
}

// Round 9
// 1341.485 us; speedup vs baseline: 3.4572x; 2.3839x over previous
//
#include <hip/hip_runtime.h>

// RelationAwareAttention: B=1, S=2048, D=1024, H=8. fp32 in / fp32 out.
// Raw reshape semantics: key(h,t) = x[8*(t&255)+h] @ attn_w[t>>8]
// Round-9: fix round-8 bug — attn_w block is selected by t (m0>>8 inside the
// Kp GEMM), NOT by the head loop. All 8 attn_w blocks pre-expanded to bf16
// hi/lo pairs; mgemm MODE 2 applies bofft=(m0>>8)*1M like round-7's gemm64.
// Split-bf16 MFMA: A*B ~= Ah*Bh+Ah*Bl+Al*Bh (PROD=3) for the logits chain;
// single product (PROD=1) for ctx/outproj. mfma_f32_16x16x32_bf16.
// ws map (72 MiB, MFMA path):
//   0 xh 4 | 4 xl 4 | 8 relh 4 | 12 rell 4 | 16 awh 16 | 32 awl 16
//   48 KpTh 4 | 52 KpTl 4          (Ph 8M aliases 48..56 after logits)
//   56 L 16                        (aliases: tmph@56 tmpl@60 rw2h@64 rw2l@66
//                                   pre-loop; ctxh@56 owh@60 post-softmax)
// Fallback: ws < 72M -> round-7 fp32 gemm64 path (40M, passing @3198us);
//           ws < 40M -> sentinel.

typedef unsigned short u16;
typedef short s16x8 __attribute__((ext_vector_type(8)));
typedef float f32x4 __attribute__((ext_vector_type(4)));

__device__ __forceinline__ float bf2f(u16 u) {
    union { unsigned int i; float f; } v; v.i = ((unsigned int)u) << 16; return v.f;
}
__device__ __forceinline__ u16 f2bf(float f) {
    unsigned int x = __float_as_uint(f);
    unsigned int r = x + 0x7fffu + ((x >> 16) & 1u);
    return (u16)(r >> 16);
}

// ---------------- sentinel diagnostic ----------------
__launch_bounds__(256)
__global__ void diag_k(float* __restrict__ out, int n, float code) {
    int i = blockIdx.x * 256 + threadIdx.x;
    if (i < n) out[i] = (i == 0) ? code : 0.f;
}

// ---------------- expand fp32 -> bf16 hi/lo ----------------
__launch_bounds__(256)
__global__ void expand_pair(const float* __restrict__ src, u16* __restrict__ hi,
                            u16* __restrict__ lo) {
    const size_t i = ((size_t)blockIdx.x * 256 + threadIdx.x) * 4;
    float4 v = *(const float4*)&src[i];
    ushort4 h, l;
    h.x = f2bf(v.x); l.x = f2bf(v.x - bf2f(h.x));
    h.y = f2bf(v.y); l.y = f2bf(v.y - bf2f(h.y));
    h.z = f2bf(v.z); l.z = f2bf(v.z - bf2f(h.z));
    h.w = f2bf(v.w); l.w = f2bf(v.w - bf2f(h.w));
    *(ushort4*)&hi[i] = h;
    *(ushort4*)&lo[i] = l;
}

__launch_bounds__(256)
__global__ void expand_hi(const float* __restrict__ src, u16* __restrict__ hi) {
    const size_t i = ((size_t)blockIdx.x * 256 + threadIdx.x) * 4;
    float4 v = *(const float4*)&src[i];
    ushort4 h;
    h.x = f2bf(v.x); h.y = f2bf(v.y); h.z = f2bf(v.z); h.w = f2bf(v.w);
    *(ushort4*)&hi[i] = h;
}

// ---------------- relation encoder layer 1 -> bf16 pair ----------------
__launch_bounds__(256)
__global__ void rel_l1_pair(const float* __restrict__ relations, const float* __restrict__ w1,
                            const float* __restrict__ b1, u16* __restrict__ th,
                            u16* __restrict__ tl) {
    const int s = blockIdx.x;
    const int d = threadIdx.x * 4;
    float4 rr = *(const float4*)(relations + s * 4);
    float4 w0 = *(const float4*)(w1 + 0 * 1024 + d);
    float4 w1r = *(const float4*)(w1 + 1 * 1024 + d);
    float4 w2r = *(const float4*)(w1 + 2 * 1024 + d);
    float4 w3r = *(const float4*)(w1 + 3 * 1024 + d);
    float4 bb = *(const float4*)(b1 + d);
    float o[4];
    o[0] = fmaxf(rr.x * w0.x + rr.y * w1r.x + rr.z * w2r.x + rr.w * w3r.x + bb.x, 0.f);
    o[1] = fmaxf(rr.x * w0.y + rr.y * w1r.y + rr.z * w2r.y + rr.w * w3r.y + bb.y, 0.f);
    o[2] = fmaxf(rr.x * w0.z + rr.y * w1r.z + rr.z * w2r.z + rr.w * w3r.z + bb.z, 0.f);
    o[3] = fmaxf(rr.x * w0.w + rr.y * w1r.w + rr.z * w2r.w + rr.w * w3r.w + bb.w, 0.f);
    ushort4 h, l;
    h.x = f2bf(o[0]); l.x = f2bf(o[0] - bf2f(h.x));
    h.y = f2bf(o[1]); l.y = f2bf(o[1] - bf2f(h.y));
    h.z = f2bf(o[2]); l.z = f2bf(o[2] - bf2f(h.z));
    h.w = f2bf(o[3]); l.w = f2bf(o[3] - bf2f(h.w));
    *(ushort4*)&th[(size_t)s * 1024 + d] = h;
    *(ushort4*)&tl[(size_t)s * 1024 + d] = l;
}

// ---------------- fp32 version (fallback path) ----------------
__launch_bounds__(256)
__global__ void rel_l1(const float* __restrict__ relations, const float* __restrict__ w1,
                       const float* __restrict__ b1, float* __restrict__ tmp) {
    const int s = blockIdx.x;
    const int d = threadIdx.x * 4;
    float4 rr = *(const float4*)(relations + s * 4);
    float4 w0 = *(const float4*)(w1 + 0 * 1024 + d);
    float4 w1r = *(const float4*)(w1 + 1 * 1024 + d);
    float4 w2r = *(const float4*)(w1 + 2 * 1024 + d);
    float4 w3r = *(const float4*)(w1 + 3 * 1024 + d);
    float4 bb = *(const float4*)(b1 + d);
    float o0 = fmaxf(rr.x * w0.x + rr.y * w1r.x + rr.z * w2r.x + rr.w * w3r.x + bb.x, 0.f);
    float o1 = fmaxf(rr.x * w0.y + rr.y * w1r.y + rr.z * w2r.y + rr.w * w3r.y + bb.y, 0.f);
    float o2 = fmaxf(rr.x * w0.z + rr.y * w1r.z + rr.z * w2r.z + rr.w * w3r.z + bb.z, 0.f);
    float o3 = fmaxf(rr.x * w0.w + rr.y * w1r.w + rr.z * w2r.w + rr.w * w3r.w + bb.w, 0.f);
    *(float4*)&tmp[(size_t)s * 1024 + d] = make_float4(o0, o1, o2, o3);
}

__launch_bounds__(256)
__global__ void init_out(const float* __restrict__ bias, float* __restrict__ oa) {
    const int s = blockIdx.x;
    const int d = threadIdx.x * 4;
    *(float4*)&oa[(size_t)s * 1024 + d] = *(const float4*)(bias + d);
}

// ============== MFMA split-bf16 GEMM: 64x64 tile, BK=32, 4 waves ==============
// MODE 0: plain; MODE 2: A-row remap (row = 8*((m0+m)&255)+head) AND B block
//         select bofft = (m0>>8)*1M (attn_w[t>>8] -- t tiles never cross 256).
// PROD 3: AhBh+AhBl+AlBh; PROD 1: AhBh only.
// OUT 0: fp32 store; 1: fp32 +=; 2: bf16-hi store; 3: bf16 pair + bias;
// OUT 4: bf16 pair, transposed (C[n][m]).
template<int MODE, int PROD, int OUT>
__launch_bounds__(256)
__global__ void mgemm(const u16* __restrict__ Ah, const u16* __restrict__ Al,
                      const u16* __restrict__ Bh, const u16* __restrict__ Bl,
                      void* __restrict__ C, u16* __restrict__ C2,
                      const float* __restrict__ bias,
                      int K, int lda, int ldb, int ldc, int head) {
    __shared__ u16 sAh[2048];
    __shared__ u16 sBh[2048];
    __shared__ u16 sAl[PROD == 3 ? 2048 : 8];
    __shared__ u16 sBl[PROD == 3 ? 2048 : 8];
    const int tid = threadIdx.x;
    const int m0 = blockIdx.y * 64, n0 = blockIdx.x * 64;

    // A staging: thread -> (m = tid>>2, kb = (tid&3)*8), 8 u16 contiguous
    const int am = tid >> 2, akb = (tid & 3) << 3;
    int grow = m0 + am;
    if (MODE == 2) grow = ((grow & 255) << 3) + head;
    const size_t aoff = (size_t)grow * lda + akb;
    const int aidx = ((am >> 4) << 9) + ((am & 15) << 3) + ((akb >> 3) << 7);
    // B staging: thread -> (n = tid&63, kb = (tid>>6)*8)
    size_t bofft = 0;
    if (MODE == 2) bofft = (size_t)(m0 >> 8) * 1048576;  // attn_w[t0>>8]
    const int bn = tid & 63, bkb = (tid >> 6) << 3;
    const size_t boff0 = bofft + (size_t)bkb * ldb + n0 + bn;
    const int bidx = ((bn >> 4) << 9) + ((bn & 15) << 3) + ((bkb >> 3) << 7);
    // wave frag bases
    const int wave = tid >> 6, lane = tid & 63;
    const int wm = (wave >> 1) << 5, wn = (wave & 1) << 5;
    const int fA = ((wm >> 4) << 9) + lane * 8;
    const int fB = ((wn >> 4) << 9) + lane * 8;

    f32x4 acc[2][2] = {{{0.f,0.f,0.f,0.f},{0.f,0.f,0.f,0.f}},
                       {{0.f,0.f,0.f,0.f},{0.f,0.f,0.f,0.f}}};

    for (int k0 = 0; k0 < K; k0 += 32) {
        // ---- stage A ----
        *(uint4*)&sAh[aidx] = *(const uint4*)(Ah + aoff + k0);
        if (PROD == 3) *(uint4*)&sAl[aidx] = *(const uint4*)(Al + aoff + k0);
        // ---- stage B (8 coalesced scalar rows, packed 16B LDS write) ----
        {
            const u16* bp = Bh + boff0 + (size_t)k0 * ldb;
            u16 vb[8];
#pragma unroll
            for (int i = 0; i < 8; ++i) vb[i] = bp[(size_t)i * ldb];
            uint4 p;
            p.x = (unsigned)vb[0] | ((unsigned)vb[1] << 16);
            p.y = (unsigned)vb[2] | ((unsigned)vb[3] << 16);
            p.z = (unsigned)vb[4] | ((unsigned)vb[5] << 16);
            p.w = (unsigned)vb[6] | ((unsigned)vb[7] << 16);
            *(uint4*)&sBh[bidx] = p;
            if (PROD == 3) {
                const u16* bpl = Bl + boff0 + (size_t)k0 * ldb;
#pragma unroll
                for (int i = 0; i < 8; ++i) vb[i] = bpl[(size_t)i * ldb];
                p.x = (unsigned)vb[0] | ((unsigned)vb[1] << 16);
                p.y = (unsigned)vb[2] | ((unsigned)vb[3] << 16);
                p.z = (unsigned)vb[4] | ((unsigned)vb[5] << 16);
                p.w = (unsigned)vb[6] | ((unsigned)vb[7] << 16);
                *(uint4*)&sBl[bidx] = p;
            }
        }
        __syncthreads();
        // ---- frags + MFMA ----
        s16x8 a0h = *(const s16x8*)&sAh[fA];
        s16x8 a1h = *(const s16x8*)&sAh[fA + 512];
        s16x8 b0h = *(const s16x8*)&sBh[fB];
        s16x8 b1h = *(const s16x8*)&sBh[fB + 512];
        acc[0][0] = __builtin_amdgcn_mfma_f32_16x16x32_bf16(a0h, b0h, acc[0][0], 0, 0, 0);
        acc[0][1] = __builtin_amdgcn_mfma_f32_16x16x32_bf16(a0h, b1h, acc[0][1], 0, 0, 0);
        acc[1][0] = __builtin_amdgcn_mfma_f32_16x16x32_bf16(a1h, b0h, acc[1][0], 0, 0, 0);
        acc[1][1] = __builtin_amdgcn_mfma_f32_16x16x32_bf16(a1h, b1h, acc[1][1], 0, 0, 0);
        if (PROD == 3) {
            s16x8 a0l = *(const s16x8*)&sAl[fA];
            s16x8 a1l = *(const s16x8*)&sAl[fA + 512];
            s16x8 b0l = *(const s16x8*)&sBl[fB];
            s16x8 b1l = *(const s16x8*)&sBl[fB + 512];
            acc[0][0] = __builtin_amdgcn_mfma_f32_16x16x32_bf16(a0h, b0l, acc[0][0], 0, 0, 0);
            acc[0][1] = __builtin_amdgcn_mfma_f32_16x16x32_bf16(a0h, b1l, acc[0][1], 0, 0, 0);
            acc[1][0] = __builtin_amdgcn_mfma_f32_16x16x32_bf16(a1h, b0l, acc[1][0], 0, 0, 0);
            acc[1][1] = __builtin_amdgcn_mfma_f32_16x16x32_bf16(a1h, b1l, acc[1][1], 0, 0, 0);
            acc[0][0] = __builtin_amdgcn_mfma_f32_16x16x32_bf16(a0l, b0h, acc[0][0], 0, 0, 0);
            acc[0][1] = __builtin_amdgcn_mfma_f32_16x16x32_bf16(a0l, b1h, acc[0][1], 0, 0, 0);
            acc[1][0] = __builtin_amdgcn_mfma_f32_16x16x32_bf16(a1l, b0h, acc[1][0], 0, 0, 0);
            acc[1][1] = __builtin_amdgcn_mfma_f32_16x16x32_bf16(a1l, b1h, acc[1][1], 0, 0, 0);
        }
        __syncthreads();
    }

    // ---- epilogue ---- C mapping: col = lane&15, row = (lane>>4)*4 + reg
    const int cc = lane & 15, q = lane >> 4;
#pragma unroll
    for (int i = 0; i < 2; ++i) {
#pragma unroll
        for (int j = 0; j < 2; ++j) {
            const int mb = m0 + wm + i * 16 + q * 4;
            const int nb = n0 + wn + j * 16 + cc;
            if (OUT == 0) {
                float* Cf = (float*)C;
#pragma unroll
                for (int r = 0; r < 4; ++r)
                    Cf[(size_t)(mb + r) * ldc + nb] = acc[i][j][r];
            } else if (OUT == 1) {
                float* Cf = (float*)C;
#pragma unroll
                for (int r = 0; r < 4; ++r)
                    Cf[(size_t)(mb + r) * ldc + nb] += acc[i][j][r];
            } else if (OUT == 2) {
                u16* Ch = (u16*)C;
#pragma unroll
                for (int r = 0; r < 4; ++r)
                    Ch[(size_t)(mb + r) * ldc + nb] = f2bf(acc[i][j][r]);
            } else if (OUT == 3) {
                u16* Ch = (u16*)C;
                float bv = bias[nb];
#pragma unroll
                for (int r = 0; r < 4; ++r) {
                    float v = acc[i][j][r] + bv;
                    u16 h = f2bf(v);
                    Ch[(size_t)(mb + r) * ldc + nb] = h;
                    C2[(size_t)(mb + r) * ldc + nb] = f2bf(v - bf2f(h));
                }
            } else {  // OUT == 4: transposed pair
                u16* Ch = (u16*)C;
                ushort4 h4, l4;
                h4.x = f2bf(acc[i][j][0]); l4.x = f2bf(acc[i][j][0] - bf2f(h4.x));
                h4.y = f2bf(acc[i][j][1]); l4.y = f2bf(acc[i][j][1] - bf2f(h4.y));
                h4.z = f2bf(acc[i][j][2]); l4.z = f2bf(acc[i][j][2] - bf2f(h4.z));
                h4.w = f2bf(acc[i][j][3]); l4.w = f2bf(acc[i][j][3] - bf2f(h4.w));
                size_t cidx = (size_t)nb * ldc + mb;
                *(ushort4*)&Ch[cidx] = h4;
                *(ushort4*)&C2[cidx] = l4;
            }
        }
    }
}

// ---------------- softmax: fp32 L row -> bf16-hi P row ----------------
__launch_bounds__(256)
__global__ void softmax_hi(const float* __restrict__ L, u16* __restrict__ Ph) {
    const int row = blockIdx.x;
    const float* p = L + (size_t)row * 2048;
    float4 v0 = ((const float4*)p)[threadIdx.x];
    float4 v1 = ((const float4*)p)[threadIdx.x + 256];
    float m = fmaxf(fmaxf(fmaxf(v0.x, v0.y), fmaxf(v0.z, v0.w)),
                    fmaxf(fmaxf(v1.x, v1.y), fmaxf(v1.z, v1.w)));
#pragma unroll
    for (int off = 32; off; off >>= 1) m = fmaxf(m, __shfl_xor(m, off));
    __shared__ float rm[4], rs[4];
    const int wave = threadIdx.x >> 6;
    if ((threadIdx.x & 63) == 0) rm[wave] = m;
    __syncthreads();
    m = fmaxf(fmaxf(rm[0], rm[1]), fmaxf(rm[2], rm[3]));
    v0.x = __expf(v0.x - m); v0.y = __expf(v0.y - m);
    v0.z = __expf(v0.z - m); v0.w = __expf(v0.w - m);
    v1.x = __expf(v1.x - m); v1.y = __expf(v1.y - m);
    v1.z = __expf(v1.z - m); v1.w = __expf(v1.w - m);
    float s = v0.x + v0.y + v0.z + v0.w + v1.x + v1.y + v1.z + v1.w;
#pragma unroll
    for (int off = 32; off; off >>= 1) s += __shfl_xor(s, off);
    if ((threadIdx.x & 63) == 0) rs[wave] = s;
    __syncthreads();
    s = rs[0] + rs[1] + rs[2] + rs[3];
    const float inv = 1.0f / s;
    ushort4 h0, h1;
    h0.x = f2bf(v0.x * inv); h0.y = f2bf(v0.y * inv);
    h0.z = f2bf(v0.z * inv); h0.w = f2bf(v0.w * inv);
    h1.x = f2bf(v1.x * inv); h1.y = f2bf(v1.y * inv);
    h1.z = f2bf(v1.z * inv); h1.w = f2bf(v1.w * inv);
    u16* o = Ph + (size_t)row * 2048;
    ((ushort4*)o)[threadIdx.x] = h0;
    ((ushort4*)o)[threadIdx.x + 256] = h1;
}

// ================= fallback: round-7 fp32 path =================
__launch_bounds__(256)
__global__ void softmax_rows(float* __restrict__ P) {
    const int row = blockIdx.x;
    float* p = P + (size_t)row * 2048;
    float4 v0 = ((const float4*)p)[threadIdx.x];
    float4 v1 = ((const float4*)p)[threadIdx.x + 256];
    float m = fmaxf(fmaxf(fmaxf(v0.x, v0.y), fmaxf(v0.z, v0.w)),
                    fmaxf(fmaxf(v1.x, v1.y), fmaxf(v1.z, v1.w)));
#pragma unroll
    for (int off = 32; off; off >>= 1) m = fmaxf(m, __shfl_xor(m, off));
    __shared__ float rm[4], rs[4];
    const int wave = threadIdx.x >> 6;
    if ((threadIdx.x & 63) == 0) rm[wave] = m;
    __syncthreads();
    m = fmaxf(fmaxf(rm[0], rm[1]), fmaxf(rm[2], rm[3]));
    v0.x = __expf(v0.x - m); v0.y = __expf(v0.y - m);
    v0.z = __expf(v0.z - m); v0.w = __expf(v0.w - m);
    v1.x = __expf(v1.x - m); v1.y = __expf(v1.y - m);
    v1.z = __expf(v1.z - m); v1.w = __expf(v1.w - m);
    float s = v0.x + v0.y + v0.z + v0.w + v1.x + v1.y + v1.z + v1.w;
#pragma unroll
    for (int off = 32; off; off >>= 1) s += __shfl_xor(s, off);
    if ((threadIdx.x & 63) == 0) rs[wave] = s;
    __syncthreads();
    s = rs[0] + rs[1] + rs[2] + rs[3];
    const float inv = 1.0f / s;
    v0.x *= inv; v0.y *= inv; v0.z *= inv; v0.w *= inv;
    v1.x *= inv; v1.y *= inv; v1.z *= inv; v1.w *= inv;
    ((float4*)p)[threadIdx.x] = v0;
    ((float4*)p)[threadIdx.x + 256] = v1;
}

constexpr int BM = 64, BN = 64, BK = 16;
constexpr int TM = 4, TN = 4;

template<int MODE, bool ACC, bool TRC>
__launch_bounds__(256)
__global__ void gemm64(const float* __restrict__ A, const float* __restrict__ B,
                       float* __restrict__ C, const float* __restrict__ bias,
                       int M, int N, int K, int lda, int ldb, int ldc,
                       int head, size_t boff) {
    __shared__ float As[BK][BM + 4];
    __shared__ float Bs[BK][BN + 4];
    const int tid = threadIdx.x;
    const int tx = tid & 15;
    const int ty = tid >> 4;
    const int m0 = blockIdx.y * BM;
    const int n0 = blockIdx.x * BN;
    size_t bofft = boff;
    if (MODE == 2) bofft += (size_t)(m0 >> 8) * 1024 * 1024;
    const int ar = tid >> 2;
    const int ac = (tid & 3) << 2;
    int grow = m0 + ar;
    if (MODE == 2) grow = ((grow & 255) << 3) + head;
    const size_t abase = (size_t)grow * lda + ac;
    const int br = tid >> 4;
    const int bc = (tid & 15) << 2;
    const size_t bbase = bofft + (size_t)br * ldb + n0 + bc;
    float acc[TM][TN];
#pragma unroll
    for (int i = 0; i < TM; ++i)
#pragma unroll
        for (int j = 0; j < TN; ++j) acc[i][j] = 0.f;
    for (int k0 = 0; k0 < K; k0 += BK) {
        float4 va = *(const float4*)(A + abase + k0);
        float4 vb = *(const float4*)(B + bbase + (size_t)k0 * ldb);
        As[ac + 0][ar] = va.x; As[ac + 1][ar] = va.y;
        As[ac + 2][ar] = va.z; As[ac + 3][ar] = va.w;
        *(float4*)&Bs[br][bc] = vb;
        __syncthreads();
#pragma unroll
        for (int k = 0; k < BK; ++k) {
            float a[TM], b[TN];
            *(float4*)&a[0] = *(const float4*)&As[k][ty * TM];
            *(float4*)&b[0] = *(const float4*)&Bs[k][tx * TN];
#pragma unroll
            for (int i = 0; i < TM; ++i)
#pragma unroll
                for (int j = 0; j < TN; ++j)
                    acc[i][j] = fmaf(a[i], b[j], acc[i][j]);
        }
        __syncthreads();
    }
    if (TRC) {
#pragma unroll
        for (int j = 0; j < TN; ++j) {
            int cn = n0 + tx * TN + j;
            size_t cidx = (size_t)cn * ldc + m0 + ty * TM;
            *(float4*)&C[cidx] = make_float4(acc[0][j], acc[1][j], acc[2][j], acc[3][j]);
        }
    } else {
        float bv[TN] = {0.f, 0.f, 0.f, 0.f};
        if (bias) {
#pragma unroll
            for (int j = 0; j < TN; ++j) bv[j] = bias[n0 + tx * TN + j];
        }
#pragma unroll
        for (int i = 0; i < TM; ++i) {
            int cm = m0 + ty * TM + i;
            size_t cidx = (size_t)cm * ldc + n0 + tx * TN;
            float4 o = make_float4(acc[i][0] + bv[0], acc[i][1] + bv[1],
                                   acc[i][2] + bv[2], acc[i][3] + bv[3]);
            if (ACC) {
                float4 old = *(const float4*)&C[cidx];
                o.x += old.x; o.y += old.y; o.z += old.z; o.w += old.w;
            }
            *(float4*)&C[cidx] = o;
        }
    }
}

extern "C" void kernel_launch(void* const* d_in, const int* in_sizes, int n_in,
                              void* d_out, int out_size, void* d_ws, size_t ws_size,
                              hipStream_t stream) {
    const float* x      = (const float*)d_in[0];
    const float* rels   = (const float*)d_in[1];
    const float* re_w1  = (const float*)d_in[2];
    const float* re_b1  = (const float*)d_in[3];
    const float* re_w2  = (const float*)d_in[4];
    const float* re_b2  = (const float*)d_in[5];
    const float* attn_w = (const float*)d_in[6];
    const float* out_w  = (const float*)d_in[7];
    const float* out_b  = (const float*)d_in[8];
    float* out = (float*)d_out;

    bool dims_ok = (n_in == 9) &&
        in_sizes[0] == 2097152 && in_sizes[1] == 8192 && in_sizes[2] == 4096 &&
        in_sizes[3] == 1024 && in_sizes[4] == 1048576 && in_sizes[5] == 1024 &&
        in_sizes[6] == 8388608 && in_sizes[7] == 8388608 && in_sizes[8] == 1024 &&
        out_size == 2097152;
    const size_t MB = 1024 * 1024;
    if (!dims_ok || ws_size < 40 * MB) {
        float code = 16384.f + (dims_ok ? 0.f : 2048.f) + 1024.f;
        diag_k<<<dim3((out_size + 255) / 256), 256, 0, stream>>>(out, out_size, code);
        return;
    }

    if (ws_size >= 72 * MB) {
        // ================= MFMA split-bf16 path =================
        char* W = (char*)d_ws;
        u16* xh   = (u16*)(W);
        u16* xl   = (u16*)(W + 4 * MB);
        u16* relh = (u16*)(W + 8 * MB);
        u16* rell = (u16*)(W + 12 * MB);
        u16* awh  = (u16*)(W + 16 * MB);   // all 8 blocks
        u16* awl  = (u16*)(W + 32 * MB);
        u16* KpTh = (u16*)(W + 48 * MB);
        u16* KpTl = (u16*)(W + 52 * MB);
        u16* Ph   = (u16*)(W + 48 * MB);   // aliases KpT pair (dead after logits)
        float* L  = (float*)(W + 56 * MB);
        u16* tmph = (u16*)(W + 56 * MB);   // pre-loop aliases of L
        u16* tmpl = (u16*)(W + 60 * MB);
        u16* rw2h = (u16*)(W + 64 * MB);
        u16* rw2l = (u16*)(W + 66 * MB);
        u16* ctxh = (u16*)(W + 56 * MB);   // post-softmax aliases of L
        u16* owh  = (u16*)(W + 60 * MB);

        expand_pair<<<dim3(2048), 256, 0, stream>>>(x, xh, xl);
        rel_l1_pair<<<dim3(2048), 256, 0, stream>>>(rels, re_w1, re_b1, tmph, tmpl);
        expand_pair<<<dim3(1024), 256, 0, stream>>>(re_w2, rw2h, rw2l);
        // rel = tmp @ re_w2 + re_b2 -> pair
        mgemm<0, 3, 3><<<dim3(16, 32), 256, 0, stream>>>(
            tmph, tmpl, rw2h, rw2l, relh, rell, re_b2, 1024, 1024, 1024, 1024, 0);
        expand_pair<<<dim3(8192), 256, 0, stream>>>(attn_w, awh, awl);
        init_out<<<dim3(2048), 256, 0, stream>>>(out_b, out);
        for (int h = 0; h < 8; ++h) {
            // KpT[d][t] = key(h,t)[d]; B block = attn_w[t>>8] via MODE-2 bofft
            mgemm<2, 3, 4><<<dim3(16, 32), 256, 0, stream>>>(
                xh, xl, awh, awl, KpTh, KpTl, nullptr, 1024, 1024, 1024, 2048, h);
            // L = rel @ KpT
            mgemm<0, 3, 0><<<dim3(32, 32), 256, 0, stream>>>(
                relh, rell, KpTh, KpTl, L, nullptr, nullptr, 1024, 1024, 2048, 2048, 0);
            softmax_hi<<<dim3(2048), 256, 0, stream>>>(L, Ph);
            expand_hi<<<dim3(1024), 256, 0, stream>>>(out_w + (size_t)h * MB, owh);
            // ctx = P @ x (single-product bf16)
            mgemm<0, 1, 2><<<dim3(16, 32), 256, 0, stream>>>(
                Ph, nullptr, xh, nullptr, ctxh, nullptr, nullptr, 2048, 2048, 1024, 1024, 0);
            // out += ctx @ out_w[h]
            mgemm<0, 1, 1><<<dim3(16, 32), 256, 0, stream>>>(
                ctxh, nullptr, owh, nullptr, out, nullptr, nullptr, 1024, 1024, 1024, 1024, 0);
        }
        return;
    }

    // ================= fallback: round-7 fp32 path =================
    float* ws  = (float*)d_ws;
    float* rel = ws;
    float* KpT = rel + 2097152;
    float* ctx = KpT + 2097152;
    float* L   = ctx + 2097152;
    float* tmp = L;

    rel_l1<<<dim3(2048), dim3(256), 0, stream>>>(rels, re_w1, re_b1, tmp);
    gemm64<0, false, false><<<dim3(16, 32), 256, 0, stream>>>(
        tmp, re_w2, rel, re_b2, 2048, 1024, 1024, 1024, 1024, 1024, 0, 0);
    init_out<<<dim3(2048), dim3(256), 0, stream>>>(out_b, out);
    for (int h = 0; h < 8; ++h) {
        gemm64<2, false, true><<<dim3(16, 32), 256, 0, stream>>>(
            x, attn_w, KpT, nullptr, 2048, 1024, 1024, 1024, 1024, 2048, h, 0);
        gemm64<0, false, false><<<dim3(32, 32), 256, 0, stream>>>(
            rel, KpT, L, nullptr, 2048, 2048, 1024, 1024, 2048, 2048, 0, 0);
        softmax_rows<<<dim3(2048), 256, 0, stream>>>(L);
        gemm64<0, false, false><<<dim3(16, 32), 256, 0, stream>>>(
            L, x, ctx, nullptr, 2048, 1024, 2048, 2048, 1024, 1024, 0, 0);
        gemm64<0, true, false><<<dim3(16, 32), 256, 0, stream>>>(
            ctx, out_w, out, nullptr, 2048, 1024, 1024, 1024, 1024, 1024,
            0, (size_t)h * 1024 * 1024);
    }
}

// Round 10
// 1199.191 us; speedup vs baseline: 3.8674x; 1.1187x over previous
//
#include <hip/hip_runtime.h>

// RelationAwareAttention: B=1, S=2048, D=1024, H=8. fp32 in / fp32 out.
// Raw reshape semantics: key(h,t) = x[8*(t&255)+h] @ attn_w[t>>8]
// Round-10: all GEMM operands K-contiguous (B pre-transposed), conflict-free
// LDS chunk layout (chunk = (m&1) + 2*kb + 8*(m>>1) -> bank group spans 8),
// 128x64 logits tile. 16x16x32 bf16 MFMA with the round-9-VERIFIED layouts:
//   A[m=lane&15][k=(lane>>4)*8+j], B^T same, C col=lane&15 row=(lane>>4)*4+reg.
// Split-bf16: PROD=3 (AhBh+AhBl+AlBh) for rel/Kp/logits; PROD=1 for ctx/outproj.
// ws map (72 MiB):
//   0 xh 4 | 4 xl | 8 relh | 12 rell | 16 awTh 16 | 32 awTl 16
//   48 Kph 4 | 52 Kpl 4   (Ph 8M aliases 48..56 after logits)
//   56 L 16  (pre-loop aliases: tmph@56 tmpl@60 rw2Th@64 rw2Tl@66;
//             post-softmax aliases: ctxh@56 owTh@60 xTh@62)
// Fallback: ws < 72M -> fp32 gemm64 path (40M); ws < 40M -> sentinel.

typedef unsigned short u16;
typedef short s16x8 __attribute__((ext_vector_type(8)));
typedef float f32x4 __attribute__((ext_vector_type(4)));

__device__ __forceinline__ float bf2f(u16 u) {
    union { unsigned int i; float f; } v; v.i = ((unsigned int)u) << 16; return v.f;
}
__device__ __forceinline__ u16 f2bf(float f) {
    unsigned int x = __float_as_uint(f);
    unsigned int r = x + 0x7fffu + ((x >> 16) & 1u);
    return (u16)(r >> 16);
}

// ---------------- sentinel ----------------
__launch_bounds__(256)
__global__ void diag_k(float* __restrict__ out, int n, float code) {
    int i = blockIdx.x * 256 + threadIdx.x;
    if (i < n) out[i] = (i == 0) ? code : 0.f;
}

// ---------------- expand fp32 -> bf16 hi/lo (natural layout) ----------------
__launch_bounds__(256)
__global__ void expand_pair(const float* __restrict__ src, u16* __restrict__ hi,
                            u16* __restrict__ lo) {
    const size_t i = ((size_t)blockIdx.x * 256 + threadIdx.x) * 4;
    float4 v = *(const float4*)&src[i];
    ushort4 h, l;
    h.x = f2bf(v.x); l.x = f2bf(v.x - bf2f(h.x));
    h.y = f2bf(v.y); l.y = f2bf(v.y - bf2f(h.y));
    h.z = f2bf(v.z); l.z = f2bf(v.z - bf2f(h.z));
    h.w = f2bf(v.w); l.w = f2bf(v.w - bf2f(h.w));
    *(ushort4*)&hi[i] = h;
    *(ushort4*)&lo[i] = l;
}

// ---------------- transpose fp32 [R][C] -> bf16 hi(/lo) [C][R] ----------------
__launch_bounds__(256)
__global__ void tr_pair(const float* __restrict__ src, u16* __restrict__ dh,
                        u16* __restrict__ dl, int R, int C) {
    __shared__ float T[32][33];
    const int bx = blockIdx.x, by = blockIdx.y;
    const int rr = threadIdx.x >> 3;        // 0..31
    const int cc = (threadIdx.x & 7) * 4;   // 0,4,..,28
    float4 v = *(const float4*)(src + (size_t)(by * 32 + rr) * C + bx * 32 + cc);
    T[rr][cc] = v.x; T[rr][cc + 1] = v.y; T[rr][cc + 2] = v.z; T[rr][cc + 3] = v.w;
    __syncthreads();
    float o0 = T[cc + 0][rr], o1 = T[cc + 1][rr], o2 = T[cc + 2][rr], o3 = T[cc + 3][rr];
    ushort4 h;
    h.x = f2bf(o0); h.y = f2bf(o1); h.z = f2bf(o2); h.w = f2bf(o3);
    size_t di = (size_t)(bx * 32 + rr) * R + by * 32 + cc;
    *(ushort4*)&dh[di] = h;
    if (dl) {
        ushort4 l;
        l.x = f2bf(o0 - bf2f(h.x)); l.y = f2bf(o1 - bf2f(h.y));
        l.z = f2bf(o2 - bf2f(h.z)); l.w = f2bf(o3 - bf2f(h.w));
        *(ushort4*)&dl[di] = l;
    }
}

// ---------------- relation encoder layer 1 -> bf16 pair ----------------
__launch_bounds__(256)
__global__ void rel_l1_pair(const float* __restrict__ relations, const float* __restrict__ w1,
                            const float* __restrict__ b1, u16* __restrict__ th,
                            u16* __restrict__ tl) {
    const int s = blockIdx.x;
    const int d = threadIdx.x * 4;
    float4 rr = *(const float4*)(relations + s * 4);
    float4 w0 = *(const float4*)(w1 + 0 * 1024 + d);
    float4 w1r = *(const float4*)(w1 + 1 * 1024 + d);
    float4 w2r = *(const float4*)(w1 + 2 * 1024 + d);
    float4 w3r = *(const float4*)(w1 + 3 * 1024 + d);
    float4 bb = *(const float4*)(b1 + d);
    float o[4];
    o[0] = fmaxf(rr.x * w0.x + rr.y * w1r.x + rr.z * w2r.x + rr.w * w3r.x + bb.x, 0.f);
    o[1] = fmaxf(rr.x * w0.y + rr.y * w1r.y + rr.z * w2r.y + rr.w * w3r.y + bb.y, 0.f);
    o[2] = fmaxf(rr.x * w0.z + rr.y * w1r.z + rr.z * w2r.z + rr.w * w3r.z + bb.z, 0.f);
    o[3] = fmaxf(rr.x * w0.w + rr.y * w1r.w + rr.z * w2r.w + rr.w * w3r.w + bb.w, 0.f);
    ushort4 h, l;
    h.x = f2bf(o[0]); l.x = f2bf(o[0] - bf2f(h.x));
    h.y = f2bf(o[1]); l.y = f2bf(o[1] - bf2f(h.y));
    h.z = f2bf(o[2]); l.z = f2bf(o[2] - bf2f(h.z));
    h.w = f2bf(o[3]); l.w = f2bf(o[3] - bf2f(h.w));
    *(ushort4*)&th[(size_t)s * 1024 + d] = h;
    *(ushort4*)&tl[(size_t)s * 1024 + d] = l;
}

__launch_bounds__(256)
__global__ void init_out(const float* __restrict__ bias, float* __restrict__ oa) {
    const int s = blockIdx.x;
    const int d = threadIdx.x * 4;
    *(float4*)&oa[(size_t)s * 1024 + d] = *(const float4*)(bias + d);
}

// ============== MFMA GEMM v2: BMxBN = (MI*32)x64, BK=32, 4 waves ==============
// Both A [M][K] and B-as-BT [N][K] are K-contiguous bf16.
// LDS chunk layout per 16-row block: chunk = (m&1) + 2*kb + 8*(m>>1)
//   (bank group = (m&1)+2*kb spans 0..7 for both staging writes & frag reads).
// MODE 0: plain. MODE 2: A-row remap grow=8*((m0+r)&255)+head, B offset
//   (m0>>8)*1M elements (attn_w[t>>8] select; tiles never cross 256 rows).
// PROD 3: AhBh+AhBl+AlBh. PROD 1: AhBh.
// OUT 0: fp32 store; 1: fp32 +=; 2: bf16-hi store; 3: bf16 pair (+bias if set).
template<int MI, int MODE, int PROD, int OUT>
__launch_bounds__(256)
__global__ void mg2(const u16* __restrict__ Ah, const u16* __restrict__ Al,
                    const u16* __restrict__ Bh, const u16* __restrict__ Bl,
                    void* __restrict__ C, u16* __restrict__ C2,
                    const float* __restrict__ bias,
                    int K, int lda, int ldb, int ldc, int head) {
    __shared__ u16 sAh[MI * 1024];
    __shared__ u16 sBh[2048];
    __shared__ u16 sAl[(PROD == 3) ? MI * 1024 : 8];
    __shared__ u16 sBl[(PROD == 3) ? 2048 : 8];
    const int tid = threadIdx.x;
    const int m0 = blockIdx.y * (MI * 32);
    const int n0 = blockIdx.x * 64;
    const int w = tid >> 6, lane = tid & 63;
    const int wmB = (w >> 1) * MI;   // first m-block (16-rows) of this wave
    const int wnB = (w & 1) * 2;     // first n-block

    // frag offset within a 512-u16 block region (verified 16x16x32 layout):
    // m = lane&15, kb = lane>>4 -> chunk = (m&1) + 2*kb + 8*(m>>1)
    const int fo = (((lane & 1) + ((lane >> 4) << 1) + (((lane & 15) >> 1) << 3)) << 3);

    size_t bofft = 0;
    if (MODE == 2) bofft = (size_t)(m0 >> 8) * 1048576;

    f32x4 acc[MI][2];
#pragma unroll
    for (int i = 0; i < MI; ++i)
#pragma unroll
        for (int j = 0; j < 2; ++j) acc[i][j] = {0.f, 0.f, 0.f, 0.f};

    for (int k0 = 0; k0 < K; k0 += 32) {
        // ---- stage A: MI*128 chunks of 8 u16 ----
#pragma unroll
        for (int cb = 0; cb < MI * 128; cb += 256) {
            int c = cb + tid;
            int mb = c >> 6, cl = c & 63;
            int m = ((cl >> 3) << 1) | (cl & 1);
            int kb = (cl >> 1) & 3;
            int rloc = mb * 16 + m;
            int grow = (MODE == 2) ? ((((m0 + rloc) & 255) << 3) + head) : (m0 + rloc);
            size_t ga = (size_t)grow * lda + k0 + kb * 8;
            *(uint4*)&sAh[c * 8] = *(const uint4*)(Ah + ga);
            if (PROD == 3) *(uint4*)&sAl[c * 8] = *(const uint4*)(Al + ga);
        }
        // ---- stage B: 256 chunks ----
        {
            int c = tid;
            int nb = c >> 6, cl = c & 63;
            int n = ((cl >> 3) << 1) | (cl & 1);
            int kb = (cl >> 1) & 3;
            size_t ga = bofft + (size_t)(n0 + nb * 16 + n) * ldb + k0 + kb * 8;
            *(uint4*)&sBh[c * 8] = *(const uint4*)(Bh + ga);
            if (PROD == 3) *(uint4*)&sBl[c * 8] = *(const uint4*)(Bl + ga);
        }
        __syncthreads();
        // ---- frags + MFMA ----
        s16x8 bh0 = *(const s16x8*)&sBh[(wnB + 0) * 512 + fo];
        s16x8 bh1 = *(const s16x8*)&sBh[(wnB + 1) * 512 + fo];
        s16x8 bl0, bl1;
        if (PROD == 3) {
            bl0 = *(const s16x8*)&sBl[(wnB + 0) * 512 + fo];
            bl1 = *(const s16x8*)&sBl[(wnB + 1) * 512 + fo];
        }
#pragma unroll
        for (int i = 0; i < MI; ++i) {
            s16x8 ah = *(const s16x8*)&sAh[(wmB + i) * 512 + fo];
            acc[i][0] = __builtin_amdgcn_mfma_f32_16x16x32_bf16(ah, bh0, acc[i][0], 0, 0, 0);
            acc[i][1] = __builtin_amdgcn_mfma_f32_16x16x32_bf16(ah, bh1, acc[i][1], 0, 0, 0);
            if (PROD == 3) {
                s16x8 al = *(const s16x8*)&sAl[(wmB + i) * 512 + fo];
                acc[i][0] = __builtin_amdgcn_mfma_f32_16x16x32_bf16(ah, bl0, acc[i][0], 0, 0, 0);
                acc[i][1] = __builtin_amdgcn_mfma_f32_16x16x32_bf16(ah, bl1, acc[i][1], 0, 0, 0);
                acc[i][0] = __builtin_amdgcn_mfma_f32_16x16x32_bf16(al, bh0, acc[i][0], 0, 0, 0);
                acc[i][1] = __builtin_amdgcn_mfma_f32_16x16x32_bf16(al, bh1, acc[i][1], 0, 0, 0);
            }
        }
        __syncthreads();
    }

    // ---- epilogue: C col=lane&15, row=(lane>>4)*4+reg ----
    const int cc = lane & 15, q = lane >> 4;
#pragma unroll
    for (int i = 0; i < MI; ++i) {
#pragma unroll
        for (int j = 0; j < 2; ++j) {
            const int mb = m0 + (wmB + i) * 16 + q * 4;
            const int nb = n0 + (wnB + j) * 16 + cc;
            if (OUT == 0) {
                float* Cf = (float*)C;
#pragma unroll
                for (int r = 0; r < 4; ++r)
                    Cf[(size_t)(mb + r) * ldc + nb] = acc[i][j][r];
            } else if (OUT == 1) {
                float* Cf = (float*)C;
#pragma unroll
                for (int r = 0; r < 4; ++r)
                    Cf[(size_t)(mb + r) * ldc + nb] += acc[i][j][r];
            } else if (OUT == 2) {
                u16* Ch = (u16*)C;
#pragma unroll
                for (int r = 0; r < 4; ++r)
                    Ch[(size_t)(mb + r) * ldc + nb] = f2bf(acc[i][j][r]);
            } else {  // OUT == 3
                u16* Ch = (u16*)C;
                float bv = bias ? bias[nb] : 0.f;
#pragma unroll
                for (int r = 0; r < 4; ++r) {
                    float v = acc[i][j][r] + bv;
                    u16 h = f2bf(v);
                    Ch[(size_t)(mb + r) * ldc + nb] = h;
                    C2[(size_t)(mb + r) * ldc + nb] = f2bf(v - bf2f(h));
                }
            }
        }
    }
}

// ---------------- softmax: fp32 L row -> bf16-hi P row ----------------
__launch_bounds__(256)
__global__ void softmax_hi(const float* __restrict__ L, u16* __restrict__ Ph) {
    const int row = blockIdx.x;
    const float* p = L + (size_t)row * 2048;
    float4 v0 = ((const float4*)p)[threadIdx.x];
    float4 v1 = ((const float4*)p)[threadIdx.x + 256];
    float m = fmaxf(fmaxf(fmaxf(v0.x, v0.y), fmaxf(v0.z, v0.w)),
                    fmaxf(fmaxf(v1.x, v1.y), fmaxf(v1.z, v1.w)));
#pragma unroll
    for (int off = 32; off; off >>= 1) m = fmaxf(m, __shfl_xor(m, off));
    __shared__ float rm[4], rs[4];
    const int wave = threadIdx.x >> 6;
    if ((threadIdx.x & 63) == 0) rm[wave] = m;
    __syncthreads();
    m = fmaxf(fmaxf(rm[0], rm[1]), fmaxf(rm[2], rm[3]));
    v0.x = __expf(v0.x - m); v0.y = __expf(v0.y - m);
    v0.z = __expf(v0.z - m); v0.w = __expf(v0.w - m);
    v1.x = __expf(v1.x - m); v1.y = __expf(v1.y - m);
    v1.z = __expf(v1.z - m); v1.w = __expf(v1.w - m);
    float s = v0.x + v0.y + v0.z + v0.w + v1.x + v1.y + v1.z + v1.w;
#pragma unroll
    for (int off = 32; off; off >>= 1) s += __shfl_xor(s, off);
    if ((threadIdx.x & 63) == 0) rs[wave] = s;
    __syncthreads();
    s = rs[0] + rs[1] + rs[2] + rs[3];
    const float inv = 1.0f / s;
    ushort4 h0, h1;
    h0.x = f2bf(v0.x * inv); h0.y = f2bf(v0.y * inv);
    h0.z = f2bf(v0.z * inv); h0.w = f2bf(v0.w * inv);
    h1.x = f2bf(v1.x * inv); h1.y = f2bf(v1.y * inv);
    h1.z = f2bf(v1.z * inv); h1.w = f2bf(v1.w * inv);
    u16* o = Ph + (size_t)row * 2048;
    ((ushort4*)o)[threadIdx.x] = h0;
    ((ushort4*)o)[threadIdx.x + 256] = h1;
}

// ================= fallback: fp32 path (rounds 6-7, passing) =================
__launch_bounds__(256)
__global__ void rel_l1(const float* __restrict__ relations, const float* __restrict__ w1,
                       const float* __restrict__ b1, float* __restrict__ tmp) {
    const int s = blockIdx.x;
    const int d = threadIdx.x * 4;
    float4 rr = *(const float4*)(relations + s * 4);
    float4 w0 = *(const float4*)(w1 + 0 * 1024 + d);
    float4 w1r = *(const float4*)(w1 + 1 * 1024 + d);
    float4 w2r = *(const float4*)(w1 + 2 * 1024 + d);
    float4 w3r = *(const float4*)(w1 + 3 * 1024 + d);
    float4 bb = *(const float4*)(b1 + d);
    float o0 = fmaxf(rr.x * w0.x + rr.y * w1r.x + rr.z * w2r.x + rr.w * w3r.x + bb.x, 0.f);
    float o1 = fmaxf(rr.x * w0.y + rr.y * w1r.y + rr.z * w2r.y + rr.w * w3r.y + bb.y, 0.f);
    float o2 = fmaxf(rr.x * w0.z + rr.y * w1r.z + rr.z * w2r.z + rr.w * w3r.z + bb.z, 0.f);
    float o3 = fmaxf(rr.x * w0.w + rr.y * w1r.w + rr.z * w2r.w + rr.w * w3r.w + bb.w, 0.f);
    *(float4*)&tmp[(size_t)s * 1024 + d] = make_float4(o0, o1, o2, o3);
}

__launch_bounds__(256)
__global__ void softmax_rows(float* __restrict__ P) {
    const int row = blockIdx.x;
    float* p = P + (size_t)row * 2048;
    float4 v0 = ((const float4*)p)[threadIdx.x];
    float4 v1 = ((const float4*)p)[threadIdx.x + 256];
    float m = fmaxf(fmaxf(fmaxf(v0.x, v0.y), fmaxf(v0.z, v0.w)),
                    fmaxf(fmaxf(v1.x, v1.y), fmaxf(v1.z, v1.w)));
#pragma unroll
    for (int off = 32; off; off >>= 1) m = fmaxf(m, __shfl_xor(m, off));
    __shared__ float rm[4], rs[4];
    const int wave = threadIdx.x >> 6;
    if ((threadIdx.x & 63) == 0) rm[wave] = m;
    __syncthreads();
    m = fmaxf(fmaxf(rm[0], rm[1]), fmaxf(rm[2], rm[3]));
    v0.x = __expf(v0.x - m); v0.y = __expf(v0.y - m);
    v0.z = __expf(v0.z - m); v0.w = __expf(v0.w - m);
    v1.x = __expf(v1.x - m); v1.y = __expf(v1.y - m);
    v1.z = __expf(v1.z - m); v1.w = __expf(v1.w - m);
    float s = v0.x + v0.y + v0.z + v0.w + v1.x + v1.y + v1.z + v1.w;
#pragma unroll
    for (int off = 32; off; off >>= 1) s += __shfl_xor(s, off);
    if ((threadIdx.x & 63) == 0) rs[wave] = s;
    __syncthreads();
    s = rs[0] + rs[1] + rs[2] + rs[3];
    const float inv = 1.0f / s;
    v0.x *= inv; v0.y *= inv; v0.z *= inv; v0.w *= inv;
    v1.x *= inv; v1.y *= inv; v1.z *= inv; v1.w *= inv;
    ((float4*)p)[threadIdx.x] = v0;
    ((float4*)p)[threadIdx.x + 256] = v1;
}

constexpr int FBM = 64, FBN = 64, FBK = 16;

template<int MODE, bool ACC, bool TRC>
__launch_bounds__(256)
__global__ void gemm64(const float* __restrict__ A, const float* __restrict__ B,
                       float* __restrict__ C, const float* __restrict__ bias,
                       int M, int N, int K, int lda, int ldb, int ldc,
                       int head, size_t boff) {
    __shared__ float As[FBK][FBM + 4];
    __shared__ float Bs[FBK][FBN + 4];
    const int tid = threadIdx.x;
    const int tx = tid & 15;
    const int ty = tid >> 4;
    const int m0 = blockIdx.y * FBM;
    const int n0 = blockIdx.x * FBN;
    size_t bofft = boff;
    if (MODE == 2) bofft += (size_t)(m0 >> 8) * 1024 * 1024;
    const int ar = tid >> 2;
    const int ac = (tid & 3) << 2;
    int grow = m0 + ar;
    if (MODE == 2) grow = ((grow & 255) << 3) + head;
    const size_t abase = (size_t)grow * lda + ac;
    const int br = tid >> 4;
    const int bc = (tid & 15) << 2;
    const size_t bbase = bofft + (size_t)br * ldb + n0 + bc;
    float acc[4][4];
#pragma unroll
    for (int i = 0; i < 4; ++i)
#pragma unroll
        for (int j = 0; j < 4; ++j) acc[i][j] = 0.f;
    for (int k0 = 0; k0 < K; k0 += FBK) {
        float4 va = *(const float4*)(A + abase + k0);
        float4 vb = *(const float4*)(B + bbase + (size_t)k0 * ldb);
        As[ac + 0][ar] = va.x; As[ac + 1][ar] = va.y;
        As[ac + 2][ar] = va.z; As[ac + 3][ar] = va.w;
        *(float4*)&Bs[br][bc] = vb;
        __syncthreads();
#pragma unroll
        for (int k = 0; k < FBK; ++k) {
            float a[4], b[4];
            *(float4*)&a[0] = *(const float4*)&As[k][ty * 4];
            *(float4*)&b[0] = *(const float4*)&Bs[k][tx * 4];
#pragma unroll
            for (int i = 0; i < 4; ++i)
#pragma unroll
                for (int j = 0; j < 4; ++j)
                    acc[i][j] = fmaf(a[i], b[j], acc[i][j]);
        }
        __syncthreads();
    }
    if (TRC) {
#pragma unroll
        for (int j = 0; j < 4; ++j) {
            int cn = n0 + tx * 4 + j;
            size_t cidx = (size_t)cn * ldc + m0 + ty * 4;
            *(float4*)&C[cidx] = make_float4(acc[0][j], acc[1][j], acc[2][j], acc[3][j]);
        }
    } else {
        float bv[4] = {0.f, 0.f, 0.f, 0.f};
        if (bias) {
#pragma unroll
            for (int j = 0; j < 4; ++j) bv[j] = bias[n0 + tx * 4 + j];
        }
#pragma unroll
        for (int i = 0; i < 4; ++i) {
            int cm = m0 + ty * 4 + i;
            size_t cidx = (size_t)cm * ldc + n0 + tx * 4;
            float4 o = make_float4(acc[i][0] + bv[0], acc[i][1] + bv[1],
                                   acc[i][2] + bv[2], acc[i][3] + bv[3]);
            if (ACC) {
                float4 old = *(const float4*)&C[cidx];
                o.x += old.x; o.y += old.y; o.z += old.z; o.w += old.w;
            }
            *(float4*)&C[cidx] = o;
        }
    }
}

extern "C" void kernel_launch(void* const* d_in, const int* in_sizes, int n_in,
                              void* d_out, int out_size, void* d_ws, size_t ws_size,
                              hipStream_t stream) {
    const float* x      = (const float*)d_in[0];
    const float* rels   = (const float*)d_in[1];
    const float* re_w1  = (const float*)d_in[2];
    const float* re_b1  = (const float*)d_in[3];
    const float* re_w2  = (const float*)d_in[4];
    const float* re_b2  = (const float*)d_in[5];
    const float* attn_w = (const float*)d_in[6];
    const float* out_w  = (const float*)d_in[7];
    const float* out_b  = (const float*)d_in[8];
    float* out = (float*)d_out;

    bool dims_ok = (n_in == 9) &&
        in_sizes[0] == 2097152 && in_sizes[1] == 8192 && in_sizes[2] == 4096 &&
        in_sizes[3] == 1024 && in_sizes[4] == 1048576 && in_sizes[5] == 1024 &&
        in_sizes[6] == 8388608 && in_sizes[7] == 8388608 && in_sizes[8] == 1024 &&
        out_size == 2097152;
    const size_t MB = 1024 * 1024;
    if (!dims_ok || ws_size < 40 * MB) {
        float code = 16384.f + (dims_ok ? 0.f : 2048.f) + 1024.f;
        diag_k<<<dim3((out_size + 255) / 256), 256, 0, stream>>>(out, out_size, code);
        return;
    }

    if (ws_size >= 72 * MB) {
        char* W = (char*)d_ws;
        u16* xh    = (u16*)(W);
        u16* xl    = (u16*)(W + 4 * MB);
        u16* relh  = (u16*)(W + 8 * MB);
        u16* rell  = (u16*)(W + 12 * MB);
        u16* awTh  = (u16*)(W + 16 * MB);   // 8 blocks of [1024 d][1024 c]
        u16* awTl  = (u16*)(W + 32 * MB);
        u16* Kph   = (u16*)(W + 48 * MB);   // [2048 t][1024 d]
        u16* Kpl   = (u16*)(W + 52 * MB);
        u16* Ph    = (u16*)(W + 48 * MB);   // aliases Kp pair post-logits
        float* L   = (float*)(W + 56 * MB);
        u16* tmph  = (u16*)(W + 56 * MB);   // pre-loop aliases of L
        u16* tmpl  = (u16*)(W + 60 * MB);
        u16* rw2Th = (u16*)(W + 64 * MB);
        u16* rw2Tl = (u16*)(W + 66 * MB);
        u16* ctxh  = (u16*)(W + 56 * MB);   // post-softmax aliases of L
        u16* owTh  = (u16*)(W + 60 * MB);
        u16* xTh   = (u16*)(W + 62 * MB);   // [1024 d][2048 t] hi

        expand_pair<<<dim3(2048), 256, 0, stream>>>(x, xh, xl);
        rel_l1_pair<<<dim3(2048), 256, 0, stream>>>(rels, re_w1, re_b1, tmph, tmpl);
        tr_pair<<<dim3(32, 32), 256, 0, stream>>>(re_w2, rw2Th, rw2Tl, 1024, 1024);
        // rel = tmp @ re_w2 + re_b2 -> pair
        mg2<2, 0, 3, 3><<<dim3(16, 32), 256, 0, stream>>>(
            tmph, tmpl, rw2Th, rw2Tl, relh, rell, re_b2, 1024, 1024, 1024, 1024, 0);
        for (int h = 0; h < 8; ++h)
            tr_pair<<<dim3(32, 32), 256, 0, stream>>>(
                attn_w + (size_t)h * MB, awTh + (size_t)h * MB, awTl + (size_t)h * MB,
                1024, 1024);
        init_out<<<dim3(2048), 256, 0, stream>>>(out_b, out);
        for (int h = 0; h < 8; ++h) {
            // Kp[t][d] = x[8*(t&255)+h] @ attn_w[t>>8]  (MODE2: A remap + B block)
            mg2<2, 2, 3, 3><<<dim3(16, 32), 256, 0, stream>>>(
                xh, xl, awTh, awTl, Kph, Kpl, nullptr, 1024, 1024, 1024, 1024, h);
            // L = rel @ Kp^T  (Kp is BT-layout [t][d] naturally)
            mg2<4, 0, 3, 0><<<dim3(32, 16), 256, 0, stream>>>(
                relh, rell, Kph, Kpl, L, nullptr, nullptr, 1024, 1024, 1024, 2048, 0);
            softmax_hi<<<dim3(2048), 256, 0, stream>>>(L, Ph);
            tr_pair<<<dim3(32, 32), 256, 0, stream>>>(
                out_w + (size_t)h * MB, owTh, nullptr, 1024, 1024);
            tr_pair<<<dim3(32, 64), 256, 0, stream>>>(x, xTh, nullptr, 2048, 1024);
            // ctx = P @ x   (B = xT [d][t])
            mg2<2, 0, 1, 2><<<dim3(16, 32), 256, 0, stream>>>(
                Ph, nullptr, xTh, nullptr, ctxh, nullptr, nullptr, 2048, 2048, 2048, 1024, 0);
            // out += ctx @ out_w[h]   (B = owT [n][d])
            mg2<2, 0, 1, 1><<<dim3(16, 32), 256, 0, stream>>>(
                ctxh, nullptr, owTh, nullptr, out, nullptr, nullptr, 1024, 1024, 1024, 1024, 0);
        }
        return;
    }

    // ================= fallback: fp32 path =================
    float* ws  = (float*)d_ws;
    float* rel = ws;
    float* KpT = rel + 2097152;
    float* ctx = KpT + 2097152;
    float* L   = ctx + 2097152;
    float* tmp = L;

    rel_l1<<<dim3(2048), dim3(256), 0, stream>>>(rels, re_w1, re_b1, tmp);
    gemm64<0, false, false><<<dim3(16, 32), 256, 0, stream>>>(
        tmp, re_w2, rel, re_b2, 2048, 1024, 1024, 1024, 1024, 1024, 0, 0);
    init_out<<<dim3(2048), dim3(256), 0, stream>>>(out_b, out);
    for (int h = 0; h < 8; ++h) {
        gemm64<2, false, true><<<dim3(16, 32), 256, 0, stream>>>(
            x, attn_w, KpT, nullptr, 2048, 1024, 1024, 1024, 1024, 2048, h, 0);
        gemm64<0, false, false><<<dim3(32, 32), 256, 0, stream>>>(
            rel, KpT, L, nullptr, 2048, 2048, 1024, 1024, 2048, 2048, 0, 0);
        softmax_rows<<<dim3(2048), 256, 0, stream>>>(L);
        gemm64<0, false, false><<<dim3(16, 32), 256, 0, stream>>>(
            L, x, ctx, nullptr, 2048, 1024, 2048, 2048, 1024, 1024, 0, 0);
        gemm64<0, true, false><<<dim3(16, 32), 256, 0, stream>>>(
            ctx, out_w, out, nullptr, 2048, 1024, 1024, 1024, 1024, 1024,
            0, (size_t)h * 1024 * 1024);
    }
}